// Round 2
// baseline (1064.679 us; speedup 1.0000x reference)
//
#include <hip/hip_runtime.h>
#include <math.h>

// Problem constants
#define N_IMAGE   128
#define N_CAPTION 32
#define N_REGION  36
#define N_WORD    24
#define EMBED     1024
#define EPSV      1e-8f

// Workspace layout (float offsets)
#define WS_W1 0            // 64*64 weight-normed out1 W
#define WS_W2 4096         // 64 weight-normed out2 row
#define WS_S  4160         // 32 captions * 24 words * 8 kernels
#define WS_QN 10304        // 32 captions * 24 words * 32 blocks
// total 34880 floats = 139,520 B

// ---------------------------------------------------------------------------
// Kernel 1: weight-norm the two linear layers (tiny, 1 block)
// ---------------------------------------------------------------------------
__global__ __launch_bounds__(64) void prep_weights_k(
    const float* __restrict__ v1, const float* __restrict__ g1,
    const float* __restrict__ v2, const float* __restrict__ g2,
    float* __restrict__ ws) {
  const int j = threadIdx.x;  // 64 threads
  float s = 0.f;
  for (int c0 = 0; c0 < 64; c0++) { float x = v1[j * 64 + c0]; s += x * x; }
  const float sc = g1[j] / sqrtf(s);
  for (int c0 = 0; c0 < 64; c0++) ws[WS_W1 + j * 64 + c0] = v1[j * 64 + c0] * sc;
  float s2 = 0.f;
  for (int c0 = 0; c0 < 64; c0++) { float x = v2[c0]; s2 += x * x; }
  ws[WS_W2 + j] = v2[j] * (g2[0] / sqrtf(s2));
}

// ---------------------------------------------------------------------------
// Kernel 2: per-caption precompute: words_sim softmax, adjacency, S[i][k],
// cap block-norms qn[w][f].  One block per caption.
// ---------------------------------------------------------------------------
__global__ __launch_bounds__(256) void cap_prep_k(
    const float* __restrict__ captions, const int* __restrict__ depends,
    const float* __restrict__ mean_k, const float* __restrict__ prec_k,
    float* __restrict__ ws) {
  __shared__ __align__(16) float capT[24][132];
  __shared__ float partB[2304];   // 4 groups * 576
  __shared__ float wsL[24][25];
  __shared__ float adjL[24][24];

  const int c = blockIdx.x, tid = threadIdx.x;
  const float* capC = captions + c * N_WORD * EMBED;

  // words_sim raw = cap @ cap^T, 4x4 register tiles, 4-way split-K
  const int g = tid / 36, t = tid % 36;
  const int i0 = (t / 6) * 4, j0 = (t % 6) * 4;
  const bool act = tid < 144;
  float acc[4][4] = {};
  for (int k0 = 0; k0 < EMBED; k0 += 128) {
    for (int idx = tid; idx < 24 * 32; idx += 256) {
      int r = idx >> 5, q = idx & 31;
      *(float4*)&capT[r][q * 4] = *(const float4*)(capC + r * EMBED + k0 + q * 4);
    }
    __syncthreads();
    if (act) {
#pragma unroll
      for (int q8 = 0; q8 < 8; q8++) {
        const int q = g * 8 + q8;
        float4 av[4], bv[4];
#pragma unroll
        for (int a = 0; a < 4; a++) av[a] = *(const float4*)&capT[i0 + a][q * 4];
#pragma unroll
        for (int b = 0; b < 4; b++) bv[b] = *(const float4*)&capT[j0 + b][q * 4];
#pragma unroll
        for (int a = 0; a < 4; a++)
#pragma unroll
          for (int b = 0; b < 4; b++)
            acc[a][b] += av[a].x * bv[b].x + av[a].y * bv[b].y +
                         av[a].z * bv[b].z + av[a].w * bv[b].w;
      }
    }
    __syncthreads();
  }
  if (act)
#pragma unroll
    for (int a = 0; a < 4; a++)
#pragma unroll
      for (int b = 0; b < 4; b++)
        partB[g * 576 + (i0 + a) * 24 + (j0 + b)] = acc[a][b];
  __syncthreads();
  for (int p = tid; p < 576; p += 256)
    wsL[p / 24][p % 24] = partB[p] + partB[p + 576] + partB[p + 1152] + partB[p + 1728];
  // clear adjacency while wsL is finishing
  {
    float* ap = &adjL[0][0];
    for (int p = tid; p < 576; p += 256) ap[p] = 0.f;
  }
  __syncthreads();
  // row softmax with lambda=4
  if (tid < 24) {
    const int i = tid;
    float m = -1e30f;
    for (int j = 0; j < 24; j++) m = fmaxf(m, wsL[i][j]);
    float ssum = 0.f;
    for (int j = 0; j < 24; j++) {
      float e = expf(4.0f * (wsL[i][j] - m));
      wsL[i][j] = e; ssum += e;
    }
    float inv = 1.0f / ssum;
    for (int j = 0; j < 24; j++) wsL[i][j] *= inv;
  }
  __syncthreads();
  // adjacency scatter: pairs 1..22 valid (pair 0 skipped per reference)
  if (tid >= 1 && tid < 23) {
    int r = depends[c * 46 + tid * 2];
    int cc = depends[c * 46 + tid * 2 + 1];
    if ((unsigned)r < 24u && (unsigned)cc < 24u) {
      adjL[r][cc] = 1.f;  // scatter-max of 1.0; races benign (same value)
      adjL[cc][r] = 1.f;
    }
  }
  __syncthreads();
  if (tid < 24) adjL[tid][tid] += 1.f;  // + eye (diag may become 2.0)
  __syncthreads();
  // S[i][k] = sum_j adj[i,j] * kw_norm[i,j,k], kw from row-l2normed adj*words_sim
  if (tid < 24) {
    const int i = tid;
    float mk[8], pk2[8];
#pragma unroll
    for (int k = 0; k < 8; k++) {
      mk[k] = mean_k[k];
      float p = prec_k[k];
      pk2[k] = 1e-14f + p * p;
    }
    float s2 = 0.f;
    for (int j = 0; j < 24; j++) {
      float a = adjL[i][j] * wsL[i][j];
      s2 += a * a;
    }
    const float inv = 1.0f / (sqrtf(s2) + EPSV);
    float accS[8] = {};
    for (int j = 0; j < 24; j++) {
      const float adj_ij = adjL[i][j];
      if (adj_ij != 0.f) {
        const float nb = adj_ij * wsL[i][j] * inv;
        float wk[8], ssum = 0.f;
#pragma unroll
        for (int k = 0; k < 8; k++) {
          float d = nb - mk[k];
          wk[k] = expf(-0.5f * d * d / pk2[k]);
          ssum += wk[k];
        }
        const float invs = adj_ij / ssum;
#pragma unroll
        for (int k = 0; k < 8; k++) accS[k] += wk[k] * invs;
      }
    }
#pragma unroll
    for (int k = 0; k < 8; k++) ws[WS_S + (c * 24 + i) * 8 + k] = accS[k];
  }
  // qn[w][f]: block norms of caption words
  for (int p = tid; p < 768; p += 256) {
    const int w = p >> 5, f = p & 31;
    const float* q = capC + w * EMBED + f * 32;
    float s = 0.f;
#pragma unroll
    for (int d = 0; d < 32; d += 4) {
      float4 v = *(const float4*)(q + d);
      s += v.x * v.x + v.y * v.y + v.z * v.z + v.w * v.w;
    }
    ws[WS_QN + (c * 24 + w) * 32 + f] = sqrtf(s);
  }
}

// ---------------------------------------------------------------------------
// Kernel 3: main — one block per (image n, caption c) pair
// ---------------------------------------------------------------------------
__global__ __launch_bounds__(256) void main_k(
    const float* __restrict__ images, const float* __restrict__ captions,
    const float* __restrict__ conv_w, const float* __restrict__ out1_b,
    const float* __restrict__ out2_b, const float* __restrict__ ws,
    float* __restrict__ out) {
  __shared__ __align__(16) float imgT[36][132];     // img k-chunk; reused as partials / W1t
  __shared__ __align__(16) float capT[24][132];     // cap k-chunk; reused as w2/b1
  __shared__ float attnL[36][25];                   // raw->normalized leaky attn
  __shared__ __align__(16) float attnT[36][28];     // softmaxed attn, [r][w]; reused as S
  __shared__ __align__(16) float ctxL[24][132];     // wctx d-chunk
  __shared__ float tnodeL[24][33];
  __shared__ __align__(16) float hiddenL[24][72];
  __shared__ float sred[24];

  const int tid = threadIdx.x;
  const int bid = blockIdx.x;
  const int n = bid >> 5, c = bid & 31;
  const float* imgN = images + n * N_REGION * EMBED;
  const float* capC = captions + c * N_WORD * EMBED;

  // ============ stage 1: attn_raw = leaky_relu(img @ cap^T) ============
  // 4x4 register tiles (36x24 outputs), 4-way split-K: 216 active threads
  const int g1 = tid / 54, t1 = tid % 54;
  const int r0 = (t1 / 6) * 4, w0s1 = (t1 % 6) * 4;
  const bool act1 = tid < 216;
  float acc1[4][4] = {};

  for (int k0 = 0; k0 < EMBED; k0 += 128) {
    for (int idx = tid; idx < 36 * 32; idx += 256) {
      int r = idx >> 5, q = idx & 31;
      *(float4*)&imgT[r][q * 4] = *(const float4*)(imgN + r * EMBED + k0 + q * 4);
    }
    for (int idx = tid; idx < 24 * 32; idx += 256) {
      int r = idx >> 5, q = idx & 31;
      *(float4*)&capT[r][q * 4] = *(const float4*)(capC + r * EMBED + k0 + q * 4);
    }
    __syncthreads();
    if (act1) {
#pragma unroll
      for (int q8 = 0; q8 < 8; q8++) {
        const int q = g1 * 8 + q8;
        float4 av[4], bv[4];
#pragma unroll
        for (int a = 0; a < 4; a++) av[a] = *(const float4*)&imgT[r0 + a][q * 4];
#pragma unroll
        for (int b = 0; b < 4; b++) bv[b] = *(const float4*)&capT[w0s1 + b][q * 4];
#pragma unroll
        for (int a = 0; a < 4; a++)
#pragma unroll
          for (int b = 0; b < 4; b++)
            acc1[a][b] += av[a].x * bv[b].x + av[a].y * bv[b].y +
                          av[a].z * bv[b].z + av[a].w * bv[b].w;
      }
    }
    __syncthreads();
  }
  {
    float* part = &imgT[0][0];  // 4*864 = 3456 floats <= 4752
    if (act1) {
#pragma unroll
      for (int a = 0; a < 4; a++)
#pragma unroll
        for (int b = 0; b < 4; b++)
          part[g1 * 864 + (r0 + a) * 24 + (w0s1 + b)] = acc1[a][b];
    }
    __syncthreads();
    for (int p = tid; p < 864; p += 256) {
      float s = part[p] + part[p + 864] + part[p + 1728] + part[p + 2592];
      attnL[p / 24][p % 24] = (s > 0.f) ? s : 0.1f * s;  // leaky_relu(0.1)
    }
    __syncthreads();
  }

  // ============ stage 2: l2norm over words (per region), softmax over regions ============
  if (tid < 36) {
    const int r = tid;
    float s = 0.f;
    for (int w = 0; w < 24; w++) { float x = attnL[r][w]; s += x * x; }
    const float inv = 1.f / (sqrtf(s) + EPSV);
    for (int w = 0; w < 24; w++) attnL[r][w] *= inv;
  }
  __syncthreads();
  if (tid < 24) {
    const int w = tid;
    float m = -1e30f;
    for (int r = 0; r < 36; r++) m = fmaxf(m, attnL[r][w]);
    float ssum = 0.f;
    for (int r = 0; r < 36; r++) {
      float e = expf(4.0f * (attnL[r][w] - m));
      attnT[r][w] = e; ssum += e;
    }
    const float inv = 1.0f / ssum;
    for (int r = 0; r < 36; r++) attnT[r][w] *= inv;
  }
  __syncthreads();

  // ============ stage 3: wctx chunks + block cosine -> tnode ============
  for (int k0 = 0; k0 < EMBED; k0 += 128) {
    for (int idx = tid; idx < 36 * 32; idx += 256) {
      int r = idx >> 5, q = idx & 31;
      *(float4*)&imgT[r][q * 4] = *(const float4*)(imgN + r * EMBED + k0 + q * 4);
    }
    for (int idx = tid; idx < 24 * 32; idx += 256) {
      int r = idx >> 5, q = idx & 31;
      *(float4*)&capT[r][q * 4] = *(const float4*)(capC + r * EMBED + k0 + q * 4);
    }
    __syncthreads();
    if (tid < 192) {  // (4 words) x (4 d) register tile per thread
      const int w0 = (tid >> 5) * 4, dq = tid & 31;
      float4 a0 = make_float4(0.f, 0.f, 0.f, 0.f), a1 = a0, a2 = a0, a3 = a0;
      for (int r = 0; r < 36; r++) {
        float4 iv = *(const float4*)&imgT[r][dq * 4];
        float4 aw = *(const float4*)&attnT[r][w0];
        a0.x += aw.x * iv.x; a0.y += aw.x * iv.y; a0.z += aw.x * iv.z; a0.w += aw.x * iv.w;
        a1.x += aw.y * iv.x; a1.y += aw.y * iv.y; a1.z += aw.y * iv.z; a1.w += aw.y * iv.w;
        a2.x += aw.z * iv.x; a2.y += aw.z * iv.y; a2.z += aw.z * iv.z; a2.w += aw.z * iv.w;
        a3.x += aw.w * iv.x; a3.y += aw.w * iv.y; a3.z += aw.w * iv.z; a3.w += aw.w * iv.w;
      }
      *(float4*)&ctxL[w0 + 0][dq * 4] = a0;
      *(float4*)&ctxL[w0 + 1][dq * 4] = a1;
      *(float4*)&ctxL[w0 + 2][dq * 4] = a2;
      *(float4*)&ctxL[w0 + 3][dq * 4] = a3;
    }
    __syncthreads();
    if (tid < 96) {  // cosine per (word, 32-block)
      const int w = tid >> 2, fl = tid & 3;
      float num = 0.f, cn2 = 0.f;
#pragma unroll
      for (int d = 0; d < 32; d += 4) {
        float4 cv = *(const float4*)&ctxL[w][fl * 32 + d];
        float4 qv = *(const float4*)&capT[w][fl * 32 + d];
        num += qv.x * cv.x + qv.y * cv.y + qv.z * cv.z + qv.w * cv.w;
        cn2 += cv.x * cv.x + cv.y * cv.y + cv.z * cv.z + cv.w * cv.w;
      }
      const int f = (k0 >> 5) + fl;
      const float qn = ws[WS_QN + (c * 24 + w) * 32 + f];
      tnodeL[w][f] = num / fmaxf(qn * sqrtf(cn2), EPSV);
    }
    __syncthreads();
  }

  // ============ stage 4: graph-conv collapse + weight-normed MLP ============
  float* W1t = &imgT[0][0];   // transposed W1: W1t[col*68 + j] = W1[j][col]; 64*68=4352 floats
  float* w2s = &capT[0][0];
  float* b1s = &capT[1][0];
  float* Ss  = &attnT[0][0];  // 192 floats S[w*8+k]
  for (int idx = tid; idx < 4096; idx += 256) {
    const int j = idx >> 6, col = idx & 63;
    W1t[col * 68 + j] = ws[WS_W1 + idx];
  }
  // FIX (R1): previous staging only covered Ss[0..127] (tid capped at 255);
  // words 16..23 read stale LDS. Full strided loop covers all 192.
  for (int p = tid; p < 192; p += 256) Ss[p] = ws[WS_S + c * 192 + p];
  if (tid < 64) w2s[tid] = ws[WS_W2 + tid];
  else if (tid < 128) b1s[tid - 64] = out1_b[tid - 64];
  __syncthreads();

  // hidden[w][k*8+o] = S[w,k] * sum_f tnode[w,f]*conv_w[k,f,o]
  for (int p = tid; p < 1536; p += 256) {
    const int w = p >> 6, col = p & 63, k = col >> 3, o = col & 7;
    const float* cw = conv_w + k * 256 + o;
    float tacc = 0.f;
#pragma unroll
    for (int f = 0; f < 32; f++) tacc += tnodeL[w][f] * cw[f * 8];
    hiddenL[w][col] = Ss[w * 8 + k] * tacc;
  }
  __syncthreads();

  // h = tanh(hidden @ W1^T + b1): each thread -> 4 consecutive j outputs
  float hv[2][4];
  {
    int pc = 0;
    for (int p = tid; p < 384; p += 256, pc++) {
      const int w = p >> 4, j0 = (p & 15) * 4;
      float ax = b1s[j0 + 0], ay = b1s[j0 + 1], az = b1s[j0 + 2], aww = b1s[j0 + 3];
      for (int col = 0; col < 64; col += 4) {
        float4 h4 = *(const float4*)&hiddenL[w][col];
        float4 wv0 = *(const float4*)&W1t[(col + 0) * 68 + j0];
        float4 wv1 = *(const float4*)&W1t[(col + 1) * 68 + j0];
        float4 wv2 = *(const float4*)&W1t[(col + 2) * 68 + j0];
        float4 wv3 = *(const float4*)&W1t[(col + 3) * 68 + j0];
        ax  += h4.x * wv0.x + h4.y * wv1.x + h4.z * wv2.x + h4.w * wv3.x;
        ay  += h4.x * wv0.y + h4.y * wv1.y + h4.z * wv2.y + h4.w * wv3.y;
        az  += h4.x * wv0.z + h4.y * wv1.z + h4.z * wv2.z + h4.w * wv3.z;
        aww += h4.x * wv0.w + h4.y * wv1.w + h4.z * wv2.w + h4.w * wv3.w;
      }
      hv[pc][0] = tanhf(ax); hv[pc][1] = tanhf(ay);
      hv[pc][2] = tanhf(az); hv[pc][3] = tanhf(aww);
    }
    __syncthreads();  // all reads of hiddenL complete before overwrite
    pc = 0;
    for (int p = tid; p < 384; p += 256, pc++) {
      const int w = p >> 4, j0 = (p & 15) * 4;
      hiddenL[w][j0 + 0] = hv[pc][0]; hiddenL[w][j0 + 1] = hv[pc][1];
      hiddenL[w][j0 + 2] = hv[pc][2]; hiddenL[w][j0 + 3] = hv[pc][3];
    }
    __syncthreads();
  }

  // s[w] = h[w]·w2 + b2; output = mean over words
  if (tid < 24) {
    const int w = tid;
    float sv = out2_b[0];
    for (int j = 0; j < 64; j++) sv += hiddenL[w][j] * w2s[j];
    sred[w] = sv;
  }
  __syncthreads();
  if (tid == 0) {
    float s = 0.f;
    for (int w = 0; w < 24; w++) s += sred[w];
    out[n * 32 + c] = s * (1.0f / 24.0f);
  }
}

// ---------------------------------------------------------------------------
extern "C" void kernel_launch(void* const* d_in, const int* in_sizes, int n_in,
                              void* d_out, int out_size, void* d_ws, size_t ws_size,
                              hipStream_t stream) {
  const float* images   = (const float*)d_in[0];
  const float* captions = (const float*)d_in[1];
  const int*   depends  = (const int*)d_in[2];
  // d_in[3] cap_lens: unused by reference math (all == N_WORD)
  const float* mean_k   = (const float*)d_in[4];
  const float* prec_k   = (const float*)d_in[5];
  const float* conv_w   = (const float*)d_in[6];
  const float* out1_v   = (const float*)d_in[7];
  const float* out1_g   = (const float*)d_in[8];
  const float* out1_b   = (const float*)d_in[9];
  const float* out2_v   = (const float*)d_in[10];
  const float* out2_g   = (const float*)d_in[11];
  const float* out2_b   = (const float*)d_in[12];
  float* ws  = (float*)d_ws;
  float* out = (float*)d_out;

  prep_weights_k<<<dim3(1), dim3(64), 0, stream>>>(out1_v, out1_g, out2_v, out2_g, ws);
  cap_prep_k<<<dim3(32), dim3(256), 0, stream>>>(captions, depends, mean_k, prec_k, ws);
  main_k<<<dim3(N_IMAGE * N_CAPTION), dim3(256), 0, stream>>>(
      images, captions, conv_w, out1_b, out2_b, ws, out);
}